// Round 1
// baseline (153.546 us; speedup 1.0000x reference)
//
#include <hip/hip_runtime.h>

#define IMG   224
#define IMG2  (IMG * IMG)          // 50176
#define HO    112
#define WO_   112
#define EMBED 192
#define BATCH 32
#define NPOS  (BATCH * HO * WO_)   // 401408
#define PPB   (HO * WO_)           // 12544 positions per batch image
#define BLK_POS 128                // 2 waves x 64 positions; 12544 % 128 == 0 -> b uniform per block
#define TPW   4                    // 16-pos tiles per wave

typedef __attribute__((ext_vector_type(8))) short short8;
typedef __attribute__((ext_vector_type(4))) float float4v;

__device__ __forceinline__ short f2bf(float f) {      // fp32 -> bf16 (RNE)
    unsigned u = __builtin_bit_cast(unsigned, f);
    u += 0x7FFFu + ((u >> 16) & 1u);
    return (short)(u >> 16);
}

// Sigmoid-GELU: x*sigmoid(1.702x). Error analysis unchanged from prior round:
// offset error ~4e-4 px, invisible next to bf16-conv quantization (0.031 vs 0.076).
__device__ __forceinline__ float fast_gelu(float a) {
    float e = __builtin_amdgcn_exp2f(a * -2.45546507f);  // exp(-1.702a)
    return a * __builtin_amdgcn_rcpf(1.0f + e);
}

// Fused: MFMA conv -> GELU -> projection -> (in-register) -> deformable resample.
// Waves are fully independent: no LDS, no __syncthreads. Block = 2 waves only to
// stay friendly to the per-CU workgroup-slot limit while fixing tail imbalance.
__global__ __launch_bounds__(128)
void fused_kernel(const float* __restrict__ x,
                  const float* __restrict__ conv_w,
                  const float* __restrict__ conv_b,
                  const float* __restrict__ off_w,
                  float* __restrict__ out) {
    const int lane = threadIdx.x & 63;
    const int wv   = threadIdx.x >> 6;
    const int col  = lane & 15;
    const int quad = lane >> 4;

    // b is block-uniform (12544 % 128 == 0): SGPR base pointers, saddr-form loads.
    const int b   = blockIdx.x / (PPB / BLK_POS);                 // /98, scalar
    const int pb0 = (blockIdx.x % (PPB / BLK_POS)) * BLK_POS + wv * 64;
    const float* __restrict__ xb = x + (size_t)b * 3 * IMG2;
    float* __restrict__ ob = out + (size_t)b * 3 * (448 * 448);

    // ---- per-lane k-slot constants (loop-invariant; was recomputed per element) ----
    int  off[8];     // 32-bit element offset of (c,dy,dx) relative to (iy0,ix0)
    bool isr[8];     // k < 27: real im2col element
    bool k27[8];     // k == 27: bias slot
#pragma unroll
    for (int j = 0; j < 8; ++j) {
        int k = quad * 8 + j;
        int c = k / 9, r9 = k % 9;
        int dy = r9 / 3, dx = r9 % 3;
        isr[j] = (k < 27);
        k27[j] = (k == 27);
        off[j] = isr[j] ? (c * IMG2 + dy * IMG + dx) : 0;
    }

    // ---- B frags (conv weights + bias slot k=27); off_w pre-scaled x2 ----
    short8 bfrag[12];
#pragma unroll
    for (int nt = 0; nt < 12; ++nt) {
        int ch = nt * 16 + col;
#pragma unroll
        for (int j = 0; j < 8; ++j) {
            int k = quad * 8 + j;
            float v = (k < 27) ? conv_w[ch * 27 + k]
                               : ((k == 27) ? conv_b[ch] : 0.0f);
            bfrag[nt][j] = f2bf(v);
        }
    }
    float owx[12], owy[12];
#pragma unroll
    for (int nt = 0; nt < 12; ++nt) {
        owx[nt] = off_w[nt * 16 + col] * 2.0f;            // * PATCH_SIZE
        owy[nt] = off_w[EMBED + nt * 16 + col] * 2.0f;
    }

    for (int it = 0; it < TPW; ++it) {
        // Tile-uniform geometry: tiles of 16 never cross a row (16 | 112), so
        // ho/wo0 are wave-uniform; div/mod happens once per tile, not per lane.
        int p   = pb0 + it * 16;
        int ho  = p / WO_;
        int wo0 = p % WO_;                 // multiple of 16
        int iy0 = 2 * ho - 1;
        int ixl = 2 * (wo0 + col) - 1;     // per-lane
        int base = iy0 * IMG + ixl;

        // ---- A-frag gather. Upper bounds are provably in-range (iy,ix <= 223);
        // invalid only when ho==0 (dy==0 row) or wo==0 (dx==0 col) -> uniform branch.
        short8 a;
        if (ho > 0 && wo0 > 0) {
#pragma unroll
            for (int j = 0; j < 8; ++j) {
                float v = isr[j] ? xb[base + off[j]] : 0.0f;   // off=0 when !isr: safe
                if (k27[j]) v = 1.0f;
                a[j] = f2bf(v);
            }
        } else {
#pragma unroll
            for (int j = 0; j < 8; ++j) {
                int k = quad * 8 + j;
                int r9 = k % 9;
                int dy = r9 / 3, dx = r9 % 3;
                bool ok = isr[j] && (iy0 + dy >= 0) && (ixl + dx >= 0);
                int ad = ok ? (base + off[j]) : 0;
                float v = ok ? xb[ad] : 0.0f;
                if (k27[j]) v = 1.0f;
                a[j] = f2bf(v);
            }
        }

        // ---- conv(MFMA) -> GELU -> 2-dim projection partials ----
        float ox[4] = {0, 0, 0, 0}, oy[4] = {0, 0, 0, 0};
#pragma unroll
        for (int nt = 0; nt < 12; ++nt) {
            float4v c = {0.0f, 0.0f, 0.0f, 0.0f};
            c = __builtin_amdgcn_mfma_f32_16x16x32_bf16(a, bfrag[nt], c, 0, 0, 0);
#pragma unroll
            for (int r = 0; r < 4; ++r) {
                float g = fast_gelu(c[r]);
                ox[r] = fmaf(g, owx[nt], ox[r]);
                oy[r] = fmaf(g, owy[nt], oy[r]);
            }
        }
        // 16-lane reduction: every lane of a quad ends holding its quad's 4 sums.
#pragma unroll
        for (int d = 1; d < 16; d <<= 1) {
#pragma unroll
            for (int r = 0; r < 4; ++r) {
                ox[r] += __shfl_xor(ox[r], d, 64);
                oy[r] += __shfl_xor(oy[r], d, 64);
            }
        }

        // ---- in-register handoff: lane -> (patch = lane>>2, px = lane&3).
        // patch>>2 == quad, so this lane's offsets are ox[patch&3] locally.
        int patch = lane >> 2;
        int rsel  = patch & 3;
        int px    = lane & 3;
        float s01x = (rsel & 1) ? ox[1] : ox[0];
        float s23x = (rsel & 1) ? ox[3] : ox[2];
        float ofx  = (rsel & 2) ? s23x : s01x;
        float s01y = (rsel & 1) ? oy[1] : oy[0];
        float s23y = (rsel & 1) ? oy[3] : oy[2];
        float ofy  = (rsel & 2) ? s23y : s01y;

        // ---- resample this tile (x rows still warm in L1 from the gather) ----
        int wo = wo0 + patch;
        float xs = 2.0f * wo + 0.25f + 0.5f * px + ofx;
        float x0f = floorf(xs);
        float wx  = xs - x0f;                       // unclamped-floor weight (ref semantics)
        int x0 = (int)x0f; x0 = min(max(x0, 0), IMG - 1);
        int xq = min(x0, IMG - 2);                  // pair base; x1 == xq+1 always
        bool selx = (x0 > xq);                      // x0 == 223 -> v00 = pair.y
        int ocol = wo * 4 + px;                     // == wo0*4 + lane: linear stores

#pragma unroll
        for (int py = 0; py < 4; ++py) {
            float ys = 2.0f * ho + 0.25f + 0.5f * py + ofy;
            float y0f = floorf(ys);
            float wy  = ys - y0f;
            int y0 = (int)y0f; y0 = min(max(y0, 0), IMG - 1);
            int dyo = (y0 < IMG - 1) ? IMG : 0;     // y1 row offset: {224, 0(clamp)}
            int rb = y0 * IMG + xq;
            int orow = (ho * 4 + py) * 448 + ocol;  // scalar part folds to SALU

#pragma unroll
            for (int c = 0; c < 3; ++c) {
                int v0 = rb + c * IMG2;
                int v1 = v0 + dyo;
                float A0 = xb[v0], A1 = xb[v0 + 1];   // +1 -> offset:4 immediate
                float B0 = xb[v1], B1 = xb[v1 + 1];
                float v00 = selx ? A1 : A0;
                float v10 = selx ? B1 : B0;
                float top = fmaf(wx, A1 - v00, v00);
                float bot = fmaf(wx, B1 - v10, v10);
                ob[c * 200704 + orow] = fmaf(wy, bot - top, top);
            }
        }
    }
}

extern "C" void kernel_launch(void* const* d_in, const int* in_sizes, int n_in,
                              void* d_out, int out_size, void* d_ws, size_t ws_size,
                              hipStream_t stream) {
    const float* x      = (const float*)d_in[0];
    const float* conv_w = (const float*)d_in[1];
    const float* conv_b = (const float*)d_in[2];
    const float* off_w  = (const float*)d_in[3];
    float* out = (float*)d_out;

    // 3136 blocks x 128 threads; each block = 2 independent waves of 64 positions.
    fused_kernel<<<NPOS / BLK_POS, 128, 0, stream>>>(x, conv_w, conv_b, off_w, out);
}